// Round 1
// 236.098 us; speedup vs baseline: 1.0399x; 1.0399x over previous
//
#include <hip/hip_runtime.h>

// ---------------------------------------------------------------------------
// CrossAttention (BLT-style patch cross-attention), MI355X gfx950
// B=2, S=4096, P=1024, D=1024, H=16, dh=64
//
// Round 8 (attention staging pipeline):
//   - K/V staged via global_load_lds (async, no reg round trip, no addr VALU)
//     into XOR-swizzled [64][64] LDS tiles (16B granule ^= row&7; source
//     address pre-swizzled, LDS dest linear)
//   - double-buffered K/V + counted s_waitcnt vmcnt(4) + raw s_barrier:
//     tile t+1's loads stay in flight under tile t's softmax+PV
//   - Ps also XOR-swizzled [64][64] (pad dropped): writes 2-way, reads 2-way
//   - LDS 40960 B -> exactly 4 blocks/CU
//   - s_setprio(1) around QK / PV MFMA clusters
//   - gemm_qkv grid compacted to dim3(8,96) (no no-op blocks)
//   - keep: fused convert+cumsum, fused QKV GEMM, gll 128-tile GEMMs,
//     sigma-permuted PV k-dimension, raw exp2, perm-packed P
// ---------------------------------------------------------------------------

#define B_ 2
#define S_ 4096
#define P_ 1024
#define D_ 1024
#define H_ 16
#define DH_ 64

#define NCONV 14336   /* convert blocks: (2097152+524288+4*262144)/256 */

typedef __attribute__((ext_vector_type(8))) short short8;
typedef __attribute__((ext_vector_type(4))) float f32x4;

#define KSCALE 0.18033688011112042f  /* 1/sqrt(64) * log2(e) */

#if __has_builtin(__builtin_amdgcn_exp2f)
#define EXP2(x) __builtin_amdgcn_exp2f(x)
#else
#define EXP2(x) exp2f(x)
#endif

static __device__ __forceinline__ unsigned short f2bf(float f) {
    unsigned int u = __float_as_uint(f);
    u += 0x7FFFu + ((u >> 16) & 1u);   // round-to-nearest-even
    return (unsigned short)(u >> 16);
}

// async 16B global -> LDS (wave-uniform lds base + lane*16)
static __device__ __forceinline__ void gll16(const unsigned short* g,
                                             const unsigned short* l) {
    __builtin_amdgcn_global_load_lds(
        (const __attribute__((address_space(1))) unsigned int*)g,
        (__attribute__((address_space(3))) unsigned int*)l,
        16, 0, 0);
}

// ---------------------------------------------------------------------------
// fused fp32 -> bf16 conversion of all six tensors + cumsum (single launch)
// ---------------------------------------------------------------------------
__global__ __launch_bounds__(256) void xattn_convert_all(
    const float* __restrict__ queries, const float* __restrict__ patches,
    const float* __restrict__ wq, const float* __restrict__ wk,
    const float* __restrict__ wv, const float* __restrict__ wo,
    unsigned short* __restrict__ qb, unsigned short* __restrict__ pb,
    unsigned short* __restrict__ wqb, unsigned short* __restrict__ wkb,
    unsigned short* __restrict__ wvb, unsigned short* __restrict__ wob,
    const int* __restrict__ bounds, int* __restrict__ pidx) {
    if (blockIdx.x >= NCONV) {
        // ---- cumsum path: one block per batch, 256 threads x 16 elems ----
        __shared__ int sdata[256];
        int b = blockIdx.x - NCONV;
        int t = threadIdx.x;
        const int* src = bounds + b * S_ + t * 16;
        int vals[16];
        int run = 0;
#pragma unroll
        for (int i = 0; i < 16; ++i) { run += src[i]; vals[i] = run; }
        sdata[t] = run;
        __syncthreads();
        for (int off = 1; off < 256; off <<= 1) {
            int v = (t >= off) ? sdata[t - off] : 0;
            __syncthreads();
            sdata[t] += v;
            __syncthreads();
        }
        int prefix = (t > 0) ? sdata[t - 1] : 0;
        int* dst = pidx + b * S_ + t * 16;
#pragma unroll
        for (int i = 0; i < 16; ++i) dst[i] = prefix + vals[i];
        return;
    }
    // ---- convert path ----
    const int NQ = (B_ * S_ * D_) / 4;      // 2097152
    const int NP = (B_ * P_ * D_) / 4;      // 524288
    const int NW = (D_ * D_) / 4;           // 262144
    int i = blockIdx.x * 256 + threadIdx.x;
    const float* src;
    unsigned short* dst;
    int j;
    if (i < NQ) { src = queries; dst = qb; j = i; }
    else if (i < NQ + NP) { src = patches; dst = pb; j = i - NQ; }
    else {
        int k = i - NQ - NP;
        int wsel = k >> 18;                  // NW = 2^18
        j = k & (NW - 1);
        if (wsel == 0) { src = wq; dst = wqb; }
        else if (wsel == 1) { src = wk; dst = wkb; }
        else if (wsel == 2) { src = wv; dst = wvb; }
        else { src = wo; dst = wob; }
    }
    float4 v = ((const float4*)src)[j];
    ushort4 o;
    o.x = f2bf(v.x); o.y = f2bf(v.y); o.z = f2bf(v.z); o.w = f2bf(v.w);
    ((ushort4*)dst)[j] = o;
}

// ---------------------------------------------------------------------------
// Fused QKV projection: 128x128 tile, global_load_lds staging, BK=32, 4 waves.
// Grid dim3(8, 96): y<64 -> Q-proj (M=8192, bf16 out * KSCALE)
//                   y in [64,80) -> K-proj (M=2048, bf16 out)
//                   y in [80,96) -> V-proj (M=2048, bf16 transposed per-head,
//                       sigma-permuted within each 64-col tile of patch dim)
// ---------------------------------------------------------------------------
__global__ __launch_bounds__(256) void xattn_gemm_qkv(
    const unsigned short* __restrict__ qb, const unsigned short* __restrict__ pb,
    const unsigned short* __restrict__ wqb, const unsigned short* __restrict__ wkb,
    const unsigned short* __restrict__ wvb,
    const float* __restrict__ bq, const float* __restrict__ bk,
    const float* __restrict__ bv,
    unsigned short* __restrict__ Qout, unsigned short* __restrict__ Kout,
    unsigned short* __restrict__ Vout) {
    const int K = 1024, N = 1024;
    const int byy = blockIdx.y;
    int z, my;
    if (byy < 64)      { z = 0; my = byy; }
    else if (byy < 80) { z = 1; my = byy - 64; }
    else               { z = 2; my = byy - 80; }
    const unsigned short* A = (z == 0) ? qb : pb;
    const unsigned short* W = (z == 0) ? wqb : ((z == 1) ? wkb : wvb);
    const float* bias = (z == 0) ? bq : ((z == 1) ? bk : bv);

    __shared__ unsigned short As[128 * 32];
    __shared__ unsigned short Bs[128 * 32];

    const int m0 = my * 128;
    const int n0 = blockIdx.x * 128;
    const int t = threadIdx.x;
    const int w = t >> 6;
    const int l = t & 63;
    const int fr = l & 15, fq = l >> 4;
    const int wr = w >> 1, wc = w & 1;

    const int r0s = t >> 2;
    const int cs = (t & 3) * 8;
    const unsigned short* Ap0 = A + (size_t)(m0 + r0s) * K + cs;
    const unsigned short* Ap1 = A + (size_t)(m0 + 64 + r0s) * K + cs;
    const unsigned short* Wp0 = W + (size_t)(n0 + r0s) * K + cs;
    const unsigned short* Wp1 = W + (size_t)(n0 + 64 + r0s) * K + cs;
    const unsigned short* lA0 = &As[(w * 64) * 8];
    const unsigned short* lA1 = &As[(256 + w * 64) * 8];
    const unsigned short* lB0 = &Bs[(w * 64) * 8];
    const unsigned short* lB1 = &Bs[(256 + w * 64) * 8];

    f32x4 acc[4][4];
#pragma unroll
    for (int i = 0; i < 4; ++i)
#pragma unroll
        for (int j = 0; j < 4; ++j) acc[i][j] = (f32x4){0.f, 0.f, 0.f, 0.f};

    for (int k0 = 0; k0 < K; k0 += 32) {
        gll16(Ap0 + k0, lA0);
        gll16(Ap1 + k0, lA1);
        gll16(Wp0 + k0, lB0);
        gll16(Wp1 + k0, lB1);
        __syncthreads();
        short8 af[4], bf[4];
#pragma unroll
        for (int i = 0; i < 4; ++i)
            af[i] = *(const short8*)&As[(wr * 64 + i * 16 + fr) * 32 + fq * 8];
#pragma unroll
        for (int j = 0; j < 4; ++j)
            bf[j] = *(const short8*)&Bs[(wc * 64 + j * 16 + fr) * 32 + fq * 8];
#pragma unroll
        for (int i = 0; i < 4; ++i)
#pragma unroll
            for (int j = 0; j < 4; ++j)
                acc[i][j] = __builtin_amdgcn_mfma_f32_16x16x32_bf16(af[i], bf[j], acc[i][j], 0, 0, 0);
        __syncthreads();
    }

#pragma unroll
    for (int j = 0; j < 4; ++j) {
        int n = n0 + wc * 64 + j * 16 + fr;
        float bvv = bias[n];
#pragma unroll
        for (int i = 0; i < 4; ++i) {
            int mbase = m0 + wr * 64 + i * 16 + fq * 4;
#pragma unroll
            for (int r = 0; r < 4; ++r) {
                float val = acc[i][j][r] + bvv;
                int m = mbase + r;
                if (z == 0) {
                    Qout[(size_t)m * N + n] = f2bf(val * KSCALE);
                } else if (z == 1) {
                    Kout[(size_t)m * N + n] = f2bf(val);
                } else {
                    int bb = m >> 10, c = m & (P_ - 1);
                    int hh = n >> 6, d = n & 63;
                    int cl = c & 63;
                    int cp = (c & 960) | (((cl & 15) << 2) | (cl >> 4)); // sigma
                    Vout[(((size_t)(bb * H_ + hh)) * 64 + d) * P_ + cp] = f2bf(val);
                }
            }
        }
    }
}

// ---------------------------------------------------------------------------
// 128x128-tile GEMM, global_load_lds staging, fp32 out (O projection).
// ---------------------------------------------------------------------------
__global__ __launch_bounds__(256) void xattn_gemm_o(
    const unsigned short* __restrict__ A,
    const unsigned short* __restrict__ W,
    const float* __restrict__ bias,
    float* __restrict__ Cout) {
    const int K = 1024, N = 1024;
    __shared__ unsigned short As[128 * 32];
    __shared__ unsigned short Bs[128 * 32];

    const int m0 = blockIdx.y * 128;
    const int n0 = blockIdx.x * 128;
    const int t = threadIdx.x;
    const int w = t >> 6;
    const int l = t & 63;
    const int fr = l & 15, fq = l >> 4;
    const int wr = w >> 1, wc = w & 1;

    const int r0s = t >> 2;
    const int cs = (t & 3) * 8;
    const unsigned short* Ap0 = A + (size_t)(m0 + r0s) * K + cs;
    const unsigned short* Ap1 = A + (size_t)(m0 + 64 + r0s) * K + cs;
    const unsigned short* Wp0 = W + (size_t)(n0 + r0s) * K + cs;
    const unsigned short* Wp1 = W + (size_t)(n0 + 64 + r0s) * K + cs;
    const unsigned short* lA0 = &As[(w * 64) * 8];
    const unsigned short* lA1 = &As[(256 + w * 64) * 8];
    const unsigned short* lB0 = &Bs[(w * 64) * 8];
    const unsigned short* lB1 = &Bs[(256 + w * 64) * 8];

    f32x4 acc[4][4];
#pragma unroll
    for (int i = 0; i < 4; ++i)
#pragma unroll
        for (int j = 0; j < 4; ++j) acc[i][j] = (f32x4){0.f, 0.f, 0.f, 0.f};

    for (int k0 = 0; k0 < K; k0 += 32) {
        gll16(Ap0 + k0, lA0);
        gll16(Ap1 + k0, lA1);
        gll16(Wp0 + k0, lB0);
        gll16(Wp1 + k0, lB1);
        __syncthreads();
        short8 af[4], bf[4];
#pragma unroll
        for (int i = 0; i < 4; ++i)
            af[i] = *(const short8*)&As[(wr * 64 + i * 16 + fr) * 32 + fq * 8];
#pragma unroll
        for (int j = 0; j < 4; ++j)
            bf[j] = *(const short8*)&Bs[(wc * 64 + j * 16 + fr) * 32 + fq * 8];
#pragma unroll
        for (int i = 0; i < 4; ++i)
#pragma unroll
            for (int j = 0; j < 4; ++j)
                acc[i][j] = __builtin_amdgcn_mfma_f32_16x16x32_bf16(af[i], bf[j], acc[i][j], 0, 0, 0);
        __syncthreads();
    }

#pragma unroll
    for (int j = 0; j < 4; ++j) {
        int n = n0 + wc * 64 + j * 16 + fr;
        float bvv = bias[n];
#pragma unroll
        for (int i = 0; i < 4; ++i) {
            int mbase = m0 + wr * 64 + i * 16 + fq * 4;
#pragma unroll
            for (int r = 0; r < 4; ++r)
                Cout[(size_t)(mbase + r) * N + n] = acc[i][j][r] + bvv;
        }
    }
}

// ---------------------------------------------------------------------------
// MFMA flash attention, round 8:
//   gll staging into XOR-swizzled [64][64] LDS, double-buffered K/V,
//   counted vmcnt(4), raw s_barrier (no vmcnt-0 drain in loop),
//   Ps [64][64] XOR-swizzled, setprio around MFMA clusters.
// Block = 4 waves, 64 q-rows. Per tile:
//   QK^T: 8 MFMA32 (Q regs, K LDS). raw v_exp_f32, boundary-only mask.
//   P pack: v_perm truncation, 4x ds_write_b64 into swizzled sigma columns.
//   PV: 8 MFMA32 (P LDS A-frags, V^T LDS B-frags; both sigma-permuted in k).
// Swizzle scheme (all three tiles): logical 16B granule g of row r is stored
// at physical granule g ^ (r&7); rows are 128 B. global_load_lds writes
// linearly (lane*16), so the *source* address carries the inverse swizzle:
// lane l (row l>>3, phys granule l&7) reads logical granule (l&7)^(l>>3).
// ---------------------------------------------------------------------------
__global__ __launch_bounds__(256) void xattn_attn_mfma(
    const unsigned short* __restrict__ Qb,   // [B*S][D] bf16 (pre-scaled)
    const unsigned short* __restrict__ Kb,   // [B*P][D] bf16
    const unsigned short* __restrict__ Vtb,  // [B][H][64][P] bf16, sigma-perm
    const int* __restrict__ pidx,
    unsigned short* __restrict__ Ob) {       // [B*S][D] bf16
    __shared__ unsigned short Ks[2][64 * 64];
    __shared__ unsigned short Vs[2][64 * 64];
    __shared__ unsigned short Ps[64 * 64];

    const int q0 = (63 - blockIdx.x) * 64;   // LPT: heavy blocks dispatch first
    const int h = blockIdx.y;
    const int b = blockIdx.z;
    const int t = threadIdx.x;
    const int w = t >> 6, l = t & 63;
    const int fr = l & 15, fq = l >> 4;

    // Q A-frags, loaded once
    const unsigned short* qrow =
        Qb + (size_t)(b * S_ + q0 + w * 16 + fr) * D_ + h * DH_ + fq * 8;
    short8 qf0 = *(const short8*)qrow;
    short8 qf1 = *(const short8*)(qrow + 32);

    int prow[4];
#pragma unroll
    for (int r = 0; r < 4; ++r)
        prow[r] = pidx[b * S_ + q0 + w * 16 + fq * 4 + r];
    const int limit = pidx[b * S_ + q0 + 63];       // monotone in s
    const int ntiles = (min(limit, P_ - 1) + 64) >> 6;
    const int nfull = (pidx[b * S_ + q0] + 1) >> 6; // tiles needing no mask

    float lsum[4] = {0.f, 0.f, 0.f, 0.f};
    f32x4 oacc[4];
#pragma unroll
    for (int nt = 0; nt < 4; ++nt) oacc[nt] = (f32x4){0.f, 0.f, 0.f, 0.f};

    // ---- staging pointers (per lane, source pre-swizzled) ----
    const int srow = l >> 3;                 // row within an 8-row gll chunk
    const int g = (l & 7) ^ srow;            // logical granule this lane feeds
    const unsigned short* kbase = Kb + (size_t)(b * P_) * D_ + h * DH_;
    const unsigned short* vbase = Vtb + (size_t)(b * H_ + h) * 64 * P_;
    // wave w stages K rows [w*16, w*16+16) and V rows [w*16, w*16+16)
    const unsigned short* kp0 = kbase + (size_t)(w * 16 + srow) * D_ + g * 8;
    const unsigned short* kp1 = kp0 + (size_t)8 * D_;
    const unsigned short* vp0 = vbase + (size_t)(w * 16 + srow) * P_ + g * 8;
    const unsigned short* vp1 = vp0 + (size_t)8 * P_;

    // prologue: stage tile 0 into buffer 0
    gll16(kp0, &Ks[0][w * 1024]);
    gll16(kp1, &Ks[0][w * 1024 + 512]);
    gll16(vp0, &Vs[0][w * 1024]);
    gll16(vp1, &Vs[0][w * 1024 + 512]);
    kp0 += (size_t)64 * D_; kp1 += (size_t)64 * D_;
    vp0 += 64; vp1 += 64;

    const int sw = (fq ^ (fr & 7)) * 8;      // swizzled read granule (shorts)
    int cur = 0;

    for (int kt = 0; kt < ntiles; ++kt) {
        // B1: all waves done reading buf[cur^1] (prev tile) -> safe to refill
        __builtin_amdgcn_s_barrier();
        if (kt + 1 < ntiles) {
            const int nb = cur ^ 1;
            gll16(kp0, &Ks[nb][w * 1024]);
            gll16(kp1, &Ks[nb][w * 1024 + 512]);
            gll16(vp0, &Vs[nb][w * 1024]);
            gll16(vp1, &Vs[nb][w * 1024 + 512]);
            kp0 += (size_t)64 * D_; kp1 += (size_t)64 * D_;
            vp0 += 64; vp1 += 64;
            // wait only for tile kt's 4 loads; kt+1's stay in flight
            asm volatile("s_waitcnt vmcnt(4)" ::: "memory");
        } else {
            asm volatile("s_waitcnt vmcnt(0)" ::: "memory");
        }
        __builtin_amdgcn_sched_barrier(0);
        // B2: every wave's tile-kt stage is complete
        __builtin_amdgcn_s_barrier();

        const unsigned short* Kc = Ks[cur];
        const unsigned short* Vc = Vs[cur];
        const int c0 = kt * 64;
        const int maskme = (kt >= nfull);

        // QK^T -> s[nt] (rows = w*16+fq*4+r, cols = nt*16+fr)
        f32x4 s[4];
        __builtin_amdgcn_s_setprio(1);
#pragma unroll
        for (int nt = 0; nt < 4; ++nt) {
            short8 kf0 = *(const short8*)&Kc[(nt * 16 + fr) * 64 + sw];
            short8 kf1 = *(const short8*)&Kc[(nt * 16 + fr) * 64 + (sw ^ 32)];
            f32x4 a = (f32x4){0.f, 0.f, 0.f, 0.f};
            a = __builtin_amdgcn_mfma_f32_16x16x32_bf16(qf0, kf0, a, 0, 0, 0);
            a = __builtin_amdgcn_mfma_f32_16x16x32_bf16(qf1, kf1, a, 0, 0, 0);
            s[nt] = a;
        }
        __builtin_amdgcn_s_setprio(0);

        // exp2 (raw) + boundary mask + lsum
        if (maskme) {
#pragma unroll
            for (int nt = 0; nt < 4; ++nt) {
                const int col = c0 + nt * 16 + fr;
#pragma unroll
                for (int r = 0; r < 4; ++r) {
                    float p = EXP2(s[nt][r]);
                    p = (col > prow[r]) ? 0.f : p;
                    s[nt][r] = p;
                    lsum[r] += p;
                }
            }
        } else {
#pragma unroll
            for (int nt = 0; nt < 4; ++nt) {
#pragma unroll
                for (int r = 0; r < 4; ++r) {
                    float p = EXP2(s[nt][r]);
                    s[nt][r] = p;
                    lsum[r] += p;
                }
            }
        }

        // pack P row-wise into sigma-permuted, XOR-swizzled columns:
        // logical 8B slot fr of row pr holds cols {nt*16+fr}, stored at
        // physical granule (fr>>1)^(pr&7), half (fr&1)
#pragma unroll
        for (int r = 0; r < 4; ++r) {
            uint2 pk;
            pk.x = __builtin_amdgcn_perm(__float_as_uint(s[1][r]),
                                         __float_as_uint(s[0][r]), 0x07060302u);
            pk.y = __builtin_amdgcn_perm(__float_as_uint(s[3][r]),
                                         __float_as_uint(s[2][r]), 0x07060302u);
            const int pr = w * 16 + fq * 4 + r;
            const int pg = (((fr >> 1) ^ (pr & 7)) << 3) | ((fr & 1) << 2);
            *(uint2*)&Ps[pr * 64 + pg] = pk;
        }

        // PV (A = P rows, B = V^T rows; k sigma-permuted on both sides)
        const int prr = (w * 16 + fr) * 64;
        short8 pf0 = *(const short8*)&Ps[prr + sw];
        short8 pf1 = *(const short8*)&Ps[prr + (sw ^ 32)];
        __builtin_amdgcn_s_setprio(1);
#pragma unroll
        for (int nt = 0; nt < 4; ++nt) {
            short8 vf0 = *(const short8*)&Vc[(nt * 16 + fr) * 64 + sw];
            short8 vf1 = *(const short8*)&Vc[(nt * 16 + fr) * 64 + (sw ^ 32)];
            oacc[nt] = __builtin_amdgcn_mfma_f32_16x16x32_bf16(pf0, vf0, oacc[nt], 0, 0, 0);
            oacc[nt] = __builtin_amdgcn_mfma_f32_16x16x32_bf16(pf1, vf1, oacc[nt], 0, 0, 0);
        }
        __builtin_amdgcn_s_setprio(0);

        cur ^= 1;
    }

    // l reduction across the 16 fr lanes of each quad-group
#pragma unroll
    for (int off = 1; off < 16; off <<= 1) {
#pragma unroll
        for (int r = 0; r < 4; ++r)
            lsum[r] += __shfl_xor(lsum[r], off);
    }
    float inv[4];
#pragma unroll
    for (int r = 0; r < 4; ++r) inv[r] = 1.0f / lsum[r];

    unsigned short* obase = Ob + (size_t)(b * S_ + q0 + w * 16) * D_ + h * DH_;
#pragma unroll
    for (int nt = 0; nt < 4; ++nt)
#pragma unroll
        for (int r = 0; r < 4; ++r)
            obase[(size_t)(fq * 4 + r) * D_ + nt * 16 + fr] =
                f2bf(oacc[nt][r] * inv[r]);
}

// ---------------------------------------------------------------------------
// launch
// ---------------------------------------------------------------------------
extern "C" void kernel_launch(void* const* d_in, const int* in_sizes, int n_in,
                              void* d_out, int out_size, void* d_ws, size_t ws_size,
                              hipStream_t stream) {
    const float* queries = (const float*)d_in[0];
    const float* patches = (const float*)d_in[1];
    const int* bounds    = (const int*)d_in[2];
    const float* wq = (const float*)d_in[3];
    const float* wk = (const float*)d_in[4];
    const float* wv = (const float*)d_in[5];
    const float* wo = (const float*)d_in[6];
    const float* bq = (const float*)d_in[7];
    const float* bk = (const float*)d_in[8];
    const float* bv = (const float*)d_in[9];
    const float* bo = (const float*)d_in[10];
    float* out = (float*)d_out;

    char* ws = (char*)d_ws;
    unsigned short* qb    = (unsigned short*)(ws + 0);          // 16777216
    unsigned short* pb    = (unsigned short*)(ws + 16777216);   // 4194304
    unsigned short* wqb   = (unsigned short*)(ws + 20971520);   // 2097152
    unsigned short* wkb   = (unsigned short*)(ws + 23068672);
    unsigned short* wvb   = (unsigned short*)(ws + 25165824);
    unsigned short* wob   = (unsigned short*)(ws + 27262976);
    unsigned short* Qbf   = (unsigned short*)(ws + 29360128);   // 16777216
    unsigned short* Kbf   = (unsigned short*)(ws + 46137344);   // 4194304
    unsigned short* Vtb   = (unsigned short*)(ws + 50331648);   // 4194304
    unsigned short* attnb = (unsigned short*)(ws + 54525952);   // 16777216
    int* pidx             = (int*)(ws + 71303168);              // 32768

    // 1. fused converts + cumsum
    xattn_convert_all<<<dim3(NCONV + B_), 256, 0, stream>>>(
        queries, patches, wq, wk, wv, wo, qb, pb, wqb, wkb, wvb, wob,
        bounds, pidx);
    // 2. fused Q/K/V projections (one launch, compact grid)
    xattn_gemm_qkv<<<dim3(8, 96), 256, 0, stream>>>(
        qb, pb, wqb, wkb, wvb, bq, bk, bv, Qbf, Kbf, Vtb);
    // 3. MFMA flash attention (dbuf gll staging, counted vmcnt)
    xattn_attn_mfma<<<dim3(S_ / 64, H_, B_), 256, 0, stream>>>(
        Qbf, Kbf, Vtb, pidx, attnb);
    // 4. output projection (fp32 out)
    xattn_gemm_o<<<dim3(8, 64), 256, 0, stream>>>(attnb, wob, bo, out);
}

// Round 2
// 235.693 us; speedup vs baseline: 1.0417x; 1.0017x over previous
//
#include <hip/hip_runtime.h>

// ---------------------------------------------------------------------------
// CrossAttention (BLT-style patch cross-attention), MI355X gfx950
// B=2, S=4096, P=1024, D=1024, H=16, dh=64
//
// Round 9 (GEMM staging pipeline):
//   - both 128x128 GEMMs (qkv, o) get the R8 attention treatment:
//     * double-buffered LDS tiles + counted s_waitcnt vmcnt(4) + raw
//       s_barrier (no vmcnt(0) drain in the K-loop)
//     * XOR-swizzled LDS: 16B granule ^= (row>>1)&3, source pre-swizzled,
//       LDS dest linear (global_load_lds writes lane*16) -> 2-way reads (free)
//     * s_setprio(1) around the 16-MFMA cluster
//   - attention kernel unchanged from R8 (conflicts measured 0; latency-bound
//     occupancy restructure deferred)
//   - keep: fused convert+cumsum, fused QKV GEMM grid(8,96), sigma-permuted
//     PV k-dimension, raw exp2, perm-packed P, dbuf attn staging
// ---------------------------------------------------------------------------

#define B_ 2
#define S_ 4096
#define P_ 1024
#define D_ 1024
#define H_ 16
#define DH_ 64

#define NCONV 14336   /* convert blocks: (2097152+524288+4*262144)/256 */

typedef __attribute__((ext_vector_type(8))) short short8;
typedef __attribute__((ext_vector_type(4))) float f32x4;

#define KSCALE 0.18033688011112042f  /* 1/sqrt(64) * log2(e) */

#if __has_builtin(__builtin_amdgcn_exp2f)
#define EXP2(x) __builtin_amdgcn_exp2f(x)
#else
#define EXP2(x) exp2f(x)
#endif

static __device__ __forceinline__ unsigned short f2bf(float f) {
    unsigned int u = __float_as_uint(f);
    u += 0x7FFFu + ((u >> 16) & 1u);   // round-to-nearest-even
    return (unsigned short)(u >> 16);
}

// async 16B global -> LDS (wave-uniform lds base + lane*16)
static __device__ __forceinline__ void gll16(const unsigned short* g,
                                             const unsigned short* l) {
    __builtin_amdgcn_global_load_lds(
        (const __attribute__((address_space(1))) unsigned int*)g,
        (__attribute__((address_space(3))) unsigned int*)l,
        16, 0, 0);
}

// ---------------------------------------------------------------------------
// fused fp32 -> bf16 conversion of all six tensors + cumsum (single launch)
// ---------------------------------------------------------------------------
__global__ __launch_bounds__(256) void xattn_convert_all(
    const float* __restrict__ queries, const float* __restrict__ patches,
    const float* __restrict__ wq, const float* __restrict__ wk,
    const float* __restrict__ wv, const float* __restrict__ wo,
    unsigned short* __restrict__ qb, unsigned short* __restrict__ pb,
    unsigned short* __restrict__ wqb, unsigned short* __restrict__ wkb,
    unsigned short* __restrict__ wvb, unsigned short* __restrict__ wob,
    const int* __restrict__ bounds, int* __restrict__ pidx) {
    if (blockIdx.x >= NCONV) {
        // ---- cumsum path: one block per batch, 256 threads x 16 elems ----
        __shared__ int sdata[256];
        int b = blockIdx.x - NCONV;
        int t = threadIdx.x;
        const int* src = bounds + b * S_ + t * 16;
        int vals[16];
        int run = 0;
#pragma unroll
        for (int i = 0; i < 16; ++i) { run += src[i]; vals[i] = run; }
        sdata[t] = run;
        __syncthreads();
        for (int off = 1; off < 256; off <<= 1) {
            int v = (t >= off) ? sdata[t - off] : 0;
            __syncthreads();
            sdata[t] += v;
            __syncthreads();
        }
        int prefix = (t > 0) ? sdata[t - 1] : 0;
        int* dst = pidx + b * S_ + t * 16;
#pragma unroll
        for (int i = 0; i < 16; ++i) dst[i] = prefix + vals[i];
        return;
    }
    // ---- convert path ----
    const int NQ = (B_ * S_ * D_) / 4;      // 2097152
    const int NP = (B_ * P_ * D_) / 4;      // 524288
    const int NW = (D_ * D_) / 4;           // 262144
    int i = blockIdx.x * 256 + threadIdx.x;
    const float* src;
    unsigned short* dst;
    int j;
    if (i < NQ) { src = queries; dst = qb; j = i; }
    else if (i < NQ + NP) { src = patches; dst = pb; j = i - NQ; }
    else {
        int k = i - NQ - NP;
        int wsel = k >> 18;                  // NW = 2^18
        j = k & (NW - 1);
        if (wsel == 0) { src = wq; dst = wqb; }
        else if (wsel == 1) { src = wk; dst = wkb; }
        else if (wsel == 2) { src = wv; dst = wvb; }
        else { src = wo; dst = wob; }
    }
    float4 v = ((const float4*)src)[j];
    ushort4 o;
    o.x = f2bf(v.x); o.y = f2bf(v.y); o.z = f2bf(v.z); o.w = f2bf(v.w);
    ((ushort4*)dst)[j] = o;
}

// ---------------------------------------------------------------------------
// Fused QKV projection: 128x128 tile, dbuf gll staging + counted vmcnt,
// XOR-swizzled LDS, BK=32, 4 waves.
// Grid dim3(8, 96): y<64 -> Q-proj (M=8192, bf16 out * KSCALE)
//                   y in [64,80) -> K-proj (M=2048, bf16 out)
//                   y in [80,96) -> V-proj (M=2048, bf16 transposed per-head,
//                       sigma-permuted within each 64-col tile of patch dim)
// Swizzle: rows are 64 B (4 x 16B granules); physical granule =
// logical ^ ((row>>1)&3). gll writes linearly (lane*16), so the source
// address carries the inverse: lane t fetches logical granule
// (t&3) ^ ((t>>3)&3) of row t>>2. Reads XOR with (fr>>1)&3.
// ---------------------------------------------------------------------------
__global__ __launch_bounds__(256) void xattn_gemm_qkv(
    const unsigned short* __restrict__ qb, const unsigned short* __restrict__ pb,
    const unsigned short* __restrict__ wqb, const unsigned short* __restrict__ wkb,
    const unsigned short* __restrict__ wvb,
    const float* __restrict__ bq, const float* __restrict__ bk,
    const float* __restrict__ bv,
    unsigned short* __restrict__ Qout, unsigned short* __restrict__ Kout,
    unsigned short* __restrict__ Vout) {
    const int K = 1024, N = 1024;
    const int byy = blockIdx.y;
    int z, my;
    if (byy < 64)      { z = 0; my = byy; }
    else if (byy < 80) { z = 1; my = byy - 64; }
    else               { z = 2; my = byy - 80; }
    const unsigned short* A = (z == 0) ? qb : pb;
    const unsigned short* W = (z == 0) ? wqb : ((z == 1) ? wkb : wvb);
    const float* bias = (z == 0) ? bq : ((z == 1) ? bk : bv);

    __shared__ unsigned short As[2][128 * 32];
    __shared__ unsigned short Bs[2][128 * 32];

    const int m0 = my * 128;
    const int n0 = blockIdx.x * 128;
    const int t = threadIdx.x;
    const int w = t >> 6;
    const int l = t & 63;
    const int fr = l & 15, fq = l >> 4;
    const int wr = w >> 1, wc = w & 1;

    const int r0s = t >> 2;
    const int csw = ((t & 3) ^ ((t >> 3) & 3)) * 8;   // pre-swizzled source
    const unsigned short* Ap0 = A + (size_t)(m0 + r0s) * K + csw;
    const unsigned short* Ap1 = A + (size_t)(m0 + 64 + r0s) * K + csw;
    const unsigned short* Wp0 = W + (size_t)(n0 + r0s) * K + csw;
    const unsigned short* Wp1 = W + (size_t)(n0 + 64 + r0s) * K + csw;

    const int gsw = (fq ^ ((fr >> 1) & 3)) * 8;       // swizzled read granule

    f32x4 acc[4][4];
#pragma unroll
    for (int i = 0; i < 4; ++i)
#pragma unroll
        for (int j = 0; j < 4; ++j) acc[i][j] = (f32x4){0.f, 0.f, 0.f, 0.f};

    // prologue: stage K-step 0 into buffer 0
    gll16(Ap0, &As[0][w * 512]);
    gll16(Ap1, &As[0][2048 + w * 512]);
    gll16(Wp0, &Bs[0][w * 512]);
    gll16(Wp1, &Bs[0][2048 + w * 512]);

    for (int kt = 0; kt < 32; ++kt) {
        __builtin_amdgcn_s_barrier();     // prev iter's readers done
        if (kt + 1 < 32) {
            const int nb = (kt + 1) & 1;
            const int ks = (kt + 1) * 32;
            gll16(Ap0 + ks, &As[nb][w * 512]);
            gll16(Ap1 + ks, &As[nb][2048 + w * 512]);
            gll16(Wp0 + ks, &Bs[nb][w * 512]);
            gll16(Wp1 + ks, &Bs[nb][2048 + w * 512]);
            asm volatile("s_waitcnt vmcnt(4)" ::: "memory");
        } else {
            asm volatile("s_waitcnt vmcnt(0)" ::: "memory");
        }
        __builtin_amdgcn_sched_barrier(0);
        __builtin_amdgcn_s_barrier();     // all waves' step-kt stage complete

        const unsigned short* Ac = As[kt & 1];
        const unsigned short* Bc = Bs[kt & 1];
        short8 af[4], bf[4];
#pragma unroll
        for (int i = 0; i < 4; ++i)
            af[i] = *(const short8*)&Ac[(wr * 64 + i * 16 + fr) * 32 + gsw];
#pragma unroll
        for (int j = 0; j < 4; ++j)
            bf[j] = *(const short8*)&Bc[(wc * 64 + j * 16 + fr) * 32 + gsw];
        __builtin_amdgcn_s_setprio(1);
#pragma unroll
        for (int i = 0; i < 4; ++i)
#pragma unroll
            for (int j = 0; j < 4; ++j)
                acc[i][j] = __builtin_amdgcn_mfma_f32_16x16x32_bf16(af[i], bf[j], acc[i][j], 0, 0, 0);
        __builtin_amdgcn_s_setprio(0);
    }

#pragma unroll
    for (int j = 0; j < 4; ++j) {
        int n = n0 + wc * 64 + j * 16 + fr;
        float bvv = bias[n];
#pragma unroll
        for (int i = 0; i < 4; ++i) {
            int mbase = m0 + wr * 64 + i * 16 + fq * 4;
#pragma unroll
            for (int r = 0; r < 4; ++r) {
                float val = acc[i][j][r] + bvv;
                int m = mbase + r;
                if (z == 0) {
                    Qout[(size_t)m * N + n] = f2bf(val * KSCALE);
                } else if (z == 1) {
                    Kout[(size_t)m * N + n] = f2bf(val);
                } else {
                    int bb = m >> 10, c = m & (P_ - 1);
                    int hh = n >> 6, d = n & 63;
                    int cl = c & 63;
                    int cp = (c & 960) | (((cl & 15) << 2) | (cl >> 4)); // sigma
                    Vout[(((size_t)(bb * H_ + hh)) * 64 + d) * P_ + cp] = f2bf(val);
                }
            }
        }
    }
}

// ---------------------------------------------------------------------------
// 128x128-tile GEMM, dbuf gll staging + counted vmcnt, XOR-swizzled LDS,
// fp32 out (O projection).
// ---------------------------------------------------------------------------
__global__ __launch_bounds__(256) void xattn_gemm_o(
    const unsigned short* __restrict__ A,
    const unsigned short* __restrict__ W,
    const float* __restrict__ bias,
    float* __restrict__ Cout) {
    const int K = 1024, N = 1024;
    __shared__ unsigned short As[2][128 * 32];
    __shared__ unsigned short Bs[2][128 * 32];

    const int m0 = blockIdx.y * 128;
    const int n0 = blockIdx.x * 128;
    const int t = threadIdx.x;
    const int w = t >> 6;
    const int l = t & 63;
    const int fr = l & 15, fq = l >> 4;
    const int wr = w >> 1, wc = w & 1;

    const int r0s = t >> 2;
    const int csw = ((t & 3) ^ ((t >> 3) & 3)) * 8;   // pre-swizzled source
    const unsigned short* Ap0 = A + (size_t)(m0 + r0s) * K + csw;
    const unsigned short* Ap1 = A + (size_t)(m0 + 64 + r0s) * K + csw;
    const unsigned short* Wp0 = W + (size_t)(n0 + r0s) * K + csw;
    const unsigned short* Wp1 = W + (size_t)(n0 + 64 + r0s) * K + csw;

    const int gsw = (fq ^ ((fr >> 1) & 3)) * 8;       // swizzled read granule

    f32x4 acc[4][4];
#pragma unroll
    for (int i = 0; i < 4; ++i)
#pragma unroll
        for (int j = 0; j < 4; ++j) acc[i][j] = (f32x4){0.f, 0.f, 0.f, 0.f};

    // prologue: stage K-step 0 into buffer 0
    gll16(Ap0, &As[0][w * 512]);
    gll16(Ap1, &As[0][2048 + w * 512]);
    gll16(Wp0, &Bs[0][w * 512]);
    gll16(Wp1, &Bs[0][2048 + w * 512]);

    for (int kt = 0; kt < 32; ++kt) {
        __builtin_amdgcn_s_barrier();
        if (kt + 1 < 32) {
            const int nb = (kt + 1) & 1;
            const int ks = (kt + 1) * 32;
            gll16(Ap0 + ks, &As[nb][w * 512]);
            gll16(Ap1 + ks, &As[nb][2048 + w * 512]);
            gll16(Wp0 + ks, &Bs[nb][w * 512]);
            gll16(Wp1 + ks, &Bs[nb][2048 + w * 512]);
            asm volatile("s_waitcnt vmcnt(4)" ::: "memory");
        } else {
            asm volatile("s_waitcnt vmcnt(0)" ::: "memory");
        }
        __builtin_amdgcn_sched_barrier(0);
        __builtin_amdgcn_s_barrier();

        const unsigned short* Ac = As[kt & 1];
        const unsigned short* Bc = Bs[kt & 1];
        short8 af[4], bf[4];
#pragma unroll
        for (int i = 0; i < 4; ++i)
            af[i] = *(const short8*)&Ac[(wr * 64 + i * 16 + fr) * 32 + gsw];
#pragma unroll
        for (int j = 0; j < 4; ++j)
            bf[j] = *(const short8*)&Bc[(wc * 64 + j * 16 + fr) * 32 + gsw];
        __builtin_amdgcn_s_setprio(1);
#pragma unroll
        for (int i = 0; i < 4; ++i)
#pragma unroll
            for (int j = 0; j < 4; ++j)
                acc[i][j] = __builtin_amdgcn_mfma_f32_16x16x32_bf16(af[i], bf[j], acc[i][j], 0, 0, 0);
        __builtin_amdgcn_s_setprio(0);
    }

#pragma unroll
    for (int j = 0; j < 4; ++j) {
        int n = n0 + wc * 64 + j * 16 + fr;
        float bvv = bias[n];
#pragma unroll
        for (int i = 0; i < 4; ++i) {
            int mbase = m0 + wr * 64 + i * 16 + fq * 4;
#pragma unroll
            for (int r = 0; r < 4; ++r)
                Cout[(size_t)(mbase + r) * N + n] = acc[i][j][r] + bvv;
        }
    }
}

// ---------------------------------------------------------------------------
// MFMA flash attention (unchanged from R8):
//   gll staging into XOR-swizzled [64][64] LDS, double-buffered K/V,
//   counted s_waitcnt vmcnt(4), raw s_barrier, setprio around MFMA clusters.
// ---------------------------------------------------------------------------
__global__ __launch_bounds__(256) void xattn_attn_mfma(
    const unsigned short* __restrict__ Qb,   // [B*S][D] bf16 (pre-scaled)
    const unsigned short* __restrict__ Kb,   // [B*P][D] bf16
    const unsigned short* __restrict__ Vtb,  // [B][H][64][P] bf16, sigma-perm
    const int* __restrict__ pidx,
    unsigned short* __restrict__ Ob) {       // [B*S][D] bf16
    __shared__ unsigned short Ks[2][64 * 64];
    __shared__ unsigned short Vs[2][64 * 64];
    __shared__ unsigned short Ps[64 * 64];

    const int q0 = (63 - blockIdx.x) * 64;   // LPT: heavy blocks dispatch first
    const int h = blockIdx.y;
    const int b = blockIdx.z;
    const int t = threadIdx.x;
    const int w = t >> 6, l = t & 63;
    const int fr = l & 15, fq = l >> 4;

    // Q A-frags, loaded once
    const unsigned short* qrow =
        Qb + (size_t)(b * S_ + q0 + w * 16 + fr) * D_ + h * DH_ + fq * 8;
    short8 qf0 = *(const short8*)qrow;
    short8 qf1 = *(const short8*)(qrow + 32);

    int prow[4];
#pragma unroll
    for (int r = 0; r < 4; ++r)
        prow[r] = pidx[b * S_ + q0 + w * 16 + fq * 4 + r];
    const int limit = pidx[b * S_ + q0 + 63];       // monotone in s
    const int ntiles = (min(limit, P_ - 1) + 64) >> 6;
    const int nfull = (pidx[b * S_ + q0] + 1) >> 6; // tiles needing no mask

    float lsum[4] = {0.f, 0.f, 0.f, 0.f};
    f32x4 oacc[4];
#pragma unroll
    for (int nt = 0; nt < 4; ++nt) oacc[nt] = (f32x4){0.f, 0.f, 0.f, 0.f};

    // ---- staging pointers (per lane, source pre-swizzled) ----
    const int srow = l >> 3;                 // row within an 8-row gll chunk
    const int g = (l & 7) ^ srow;            // logical granule this lane feeds
    const unsigned short* kbase = Kb + (size_t)(b * P_) * D_ + h * DH_;
    const unsigned short* vbase = Vtb + (size_t)(b * H_ + h) * 64 * P_;
    // wave w stages K rows [w*16, w*16+16) and V rows [w*16, w*16+16)
    const unsigned short* kp0 = kbase + (size_t)(w * 16 + srow) * D_ + g * 8;
    const unsigned short* kp1 = kp0 + (size_t)8 * D_;
    const unsigned short* vp0 = vbase + (size_t)(w * 16 + srow) * P_ + g * 8;
    const unsigned short* vp1 = vp0 + (size_t)8 * P_;

    // prologue: stage tile 0 into buffer 0
    gll16(kp0, &Ks[0][w * 1024]);
    gll16(kp1, &Ks[0][w * 1024 + 512]);
    gll16(vp0, &Vs[0][w * 1024]);
    gll16(vp1, &Vs[0][w * 1024 + 512]);
    kp0 += (size_t)64 * D_; kp1 += (size_t)64 * D_;
    vp0 += 64; vp1 += 64;

    const int sw = (fq ^ (fr & 7)) * 8;      // swizzled read granule (shorts)
    int cur = 0;

    for (int kt = 0; kt < ntiles; ++kt) {
        // B1: all waves done reading buf[cur^1] (prev tile) -> safe to refill
        __builtin_amdgcn_s_barrier();
        if (kt + 1 < ntiles) {
            const int nb = cur ^ 1;
            gll16(kp0, &Ks[nb][w * 1024]);
            gll16(kp1, &Ks[nb][w * 1024 + 512]);
            gll16(vp0, &Vs[nb][w * 1024]);
            gll16(vp1, &Vs[nb][w * 1024 + 512]);
            kp0 += (size_t)64 * D_; kp1 += (size_t)64 * D_;
            vp0 += 64; vp1 += 64;
            // wait only for tile kt's 4 loads; kt+1's stay in flight
            asm volatile("s_waitcnt vmcnt(4)" ::: "memory");
        } else {
            asm volatile("s_waitcnt vmcnt(0)" ::: "memory");
        }
        __builtin_amdgcn_sched_barrier(0);
        // B2: every wave's tile-kt stage is complete
        __builtin_amdgcn_s_barrier();

        const unsigned short* Kc = Ks[cur];
        const unsigned short* Vc = Vs[cur];
        const int c0 = kt * 64;
        const int maskme = (kt >= nfull);

        // QK^T -> s[nt] (rows = w*16+fq*4+r, cols = nt*16+fr)
        f32x4 s[4];
        __builtin_amdgcn_s_setprio(1);
#pragma unroll
        for (int nt = 0; nt < 4; ++nt) {
            short8 kf0 = *(const short8*)&Kc[(nt * 16 + fr) * 64 + sw];
            short8 kf1 = *(const short8*)&Kc[(nt * 16 + fr) * 64 + (sw ^ 32)];
            f32x4 a = (f32x4){0.f, 0.f, 0.f, 0.f};
            a = __builtin_amdgcn_mfma_f32_16x16x32_bf16(qf0, kf0, a, 0, 0, 0);
            a = __builtin_amdgcn_mfma_f32_16x16x32_bf16(qf1, kf1, a, 0, 0, 0);
            s[nt] = a;
        }
        __builtin_amdgcn_s_setprio(0);

        // exp2 (raw) + boundary mask + lsum
        if (maskme) {
#pragma unroll
            for (int nt = 0; nt < 4; ++nt) {
                const int col = c0 + nt * 16 + fr;
#pragma unroll
                for (int r = 0; r < 4; ++r) {
                    float p = EXP2(s[nt][r]);
                    p = (col > prow[r]) ? 0.f : p;
                    s[nt][r] = p;
                    lsum[r] += p;
                }
            }
        } else {
#pragma unroll
            for (int nt = 0; nt < 4; ++nt) {
#pragma unroll
                for (int r = 0; r < 4; ++r) {
                    float p = EXP2(s[nt][r]);
                    s[nt][r] = p;
                    lsum[r] += p;
                }
            }
        }

        // pack P row-wise into sigma-permuted, XOR-swizzled columns:
        // logical 8B slot fr of row pr holds cols {nt*16+fr}, stored at
        // physical granule (fr>>1)^(pr&7), half (fr&1)
#pragma unroll
        for (int r = 0; r < 4; ++r) {
            uint2 pk;
            pk.x = __builtin_amdgcn_perm(__float_as_uint(s[1][r]),
                                         __float_as_uint(s[0][r]), 0x07060302u);
            pk.y = __builtin_amdgcn_perm(__float_as_uint(s[3][r]),
                                         __float_as_uint(s[2][r]), 0x07060302u);
            const int pr = w * 16 + fq * 4 + r;
            const int pg = (((fr >> 1) ^ (pr & 7)) << 3) | ((fr & 1) << 2);
            *(uint2*)&Ps[pr * 64 + pg] = pk;
        }

        // PV (A = P rows, B = V^T rows; k sigma-permuted on both sides)
        const int prr = (w * 16 + fr) * 64;
        short8 pf0 = *(const short8*)&Ps[prr + sw];
        short8 pf1 = *(const short8*)&Ps[prr + (sw ^ 32)];
        __builtin_amdgcn_s_setprio(1);
#pragma unroll
        for (int nt = 0; nt < 4; ++nt) {
            short8 vf0 = *(const short8*)&Vc[(nt * 16 + fr) * 64 + sw];
            short8 vf1 = *(const short8*)&Vc[(nt * 16 + fr) * 64 + (sw ^ 32)];
            oacc[nt] = __builtin_amdgcn_mfma_f32_16x16x32_bf16(pf0, vf0, oacc[nt], 0, 0, 0);
            oacc[nt] = __builtin_amdgcn_mfma_f32_16x16x32_bf16(pf1, vf1, oacc[nt], 0, 0, 0);
        }
        __builtin_amdgcn_s_setprio(0);

        cur ^= 1;
    }

    // l reduction across the 16 fr lanes of each quad-group
#pragma unroll
    for (int off = 1; off < 16; off <<= 1) {
#pragma unroll
        for (int r = 0; r < 4; ++r)
            lsum[r] += __shfl_xor(lsum[r], off);
    }
    float inv[4];
#pragma unroll
    for (int r = 0; r < 4; ++r) inv[r] = 1.0f / lsum[r];

    unsigned short* obase = Ob + (size_t)(b * S_ + q0 + w * 16) * D_ + h * DH_;
#pragma unroll
    for (int nt = 0; nt < 4; ++nt)
#pragma unroll
        for (int r = 0; r < 4; ++r)
            obase[(size_t)(fq * 4 + r) * D_ + nt * 16 + fr] =
                f2bf(oacc[nt][r] * inv[r]);
}

// ---------------------------------------------------------------------------
// launch
// ---------------------------------------------------------------------------
extern "C" void kernel_launch(void* const* d_in, const int* in_sizes, int n_in,
                              void* d_out, int out_size, void* d_ws, size_t ws_size,
                              hipStream_t stream) {
    const float* queries = (const float*)d_in[0];
    const float* patches = (const float*)d_in[1];
    const int* bounds    = (const int*)d_in[2];
    const float* wq = (const float*)d_in[3];
    const float* wk = (const float*)d_in[4];
    const float* wv = (const float*)d_in[5];
    const float* wo = (const float*)d_in[6];
    const float* bq = (const float*)d_in[7];
    const float* bk = (const float*)d_in[8];
    const float* bv = (const float*)d_in[9];
    const float* bo = (const float*)d_in[10];
    float* out = (float*)d_out;

    char* ws = (char*)d_ws;
    unsigned short* qb    = (unsigned short*)(ws + 0);          // 16777216
    unsigned short* pb    = (unsigned short*)(ws + 16777216);   // 4194304
    unsigned short* wqb   = (unsigned short*)(ws + 20971520);   // 2097152
    unsigned short* wkb   = (unsigned short*)(ws + 23068672);
    unsigned short* wvb   = (unsigned short*)(ws + 25165824);
    unsigned short* wob   = (unsigned short*)(ws + 27262976);
    unsigned short* Qbf   = (unsigned short*)(ws + 29360128);   // 16777216
    unsigned short* Kbf   = (unsigned short*)(ws + 46137344);   // 4194304
    unsigned short* Vtb   = (unsigned short*)(ws + 50331648);   // 4194304
    unsigned short* attnb = (unsigned short*)(ws + 54525952);   // 16777216
    int* pidx             = (int*)(ws + 71303168);              // 32768

    // 1. fused converts + cumsum
    xattn_convert_all<<<dim3(NCONV + B_), 256, 0, stream>>>(
        queries, patches, wq, wk, wv, wo, qb, pb, wqb, wkb, wvb, wob,
        bounds, pidx);
    // 2. fused Q/K/V projections (one launch, compact grid, dbuf pipeline)
    xattn_gemm_qkv<<<dim3(8, 96), 256, 0, stream>>>(
        qb, pb, wqb, wkb, wvb, bq, bk, bv, Qbf, Kbf, Vtb);
    // 3. MFMA flash attention (dbuf gll staging, counted vmcnt)
    xattn_attn_mfma<<<dim3(S_ / 64, H_, B_), 256, 0, stream>>>(
        Qbf, Kbf, Vtb, pidx, attnb);
    // 4. output projection (fp32 out, dbuf pipeline)
    xattn_gemm_o<<<dim3(8, 64), 256, 0, stream>>>(attnb, wob, bo, out);
}

// Round 3
// 233.288 us; speedup vs baseline: 1.0524x; 1.0103x over previous
//
#include <hip/hip_runtime.h>

// ---------------------------------------------------------------------------
// CrossAttention (BLT-style patch cross-attention), MI355X gfx950
// B=2, S=4096, P=1024, D=1024, H=16, dh=64
//
// Round 10 (attention 32x32 swapped-QK restructure):
//   - attn: 128 q-rows/block, wave=32q, mfma_f32_32x32x16_bf16
//     * QK^T computed SWAPPED (S^T = mfma(K,Q)) -> each lane owns one q col;
//       softmax fully in-register; P->bf16 A-frags via v_cvt_pk_bf16_f32 +
//       v_permlane32_swap_b32 (no Ps LDS buffer at all)
//     * K,V stored FRAGMENT-LINEAR in global (written by QKV-GEMM epilogue)
//       -> attn LDS reads are lane-linear ds_read_b128, zero conflicts
//     * LDS 32KB (2x8K K + 2x8K V dbuf), counted vmcnt(4), raw barriers
//   - GEMMs unchanged from R9 (dbuf gll + XOR swizzle + counted vmcnt)
//   - keep: fused convert+cumsum, fused QKV GEMM grid(8,96), raw exp2
// ---------------------------------------------------------------------------

#define B_ 2
#define S_ 4096
#define P_ 1024
#define D_ 1024
#define H_ 16
#define DH_ 64

#define NCONV 14336   /* convert blocks: (2097152+524288+4*262144)/256 */

typedef __attribute__((ext_vector_type(8))) short short8;
typedef __attribute__((ext_vector_type(4))) float f32x4;
typedef __attribute__((ext_vector_type(16))) float f32x16;

#define KSCALE 0.18033688011112042f  /* 1/sqrt(64) * log2(e) */

#if __has_builtin(__builtin_amdgcn_exp2f)
#define EXP2(x) __builtin_amdgcn_exp2f(x)
#else
#define EXP2(x) exp2f(x)
#endif

static __device__ __forceinline__ unsigned short f2bf(float f) {
    unsigned int u = __float_as_uint(f);
    u += 0x7FFFu + ((u >> 16) & 1u);   // round-to-nearest-even
    return (unsigned short)(u >> 16);
}

// packed f32->bf16 pair (RTNE), no builtin on gfx950
static __device__ __forceinline__ unsigned int cvtpk(float lo, float hi) {
    unsigned int r;
    asm("v_cvt_pk_bf16_f32 %0, %1, %2" : "=v"(r) : "v"(lo), "v"(hi));
    return r;
}

// x' = [x.row0, y.row0] ; y' = [x.row1, y.row1]  (rows = 32-lane halves)
static __device__ __forceinline__ void plswap(unsigned int& x, unsigned int& y) {
    asm volatile("v_permlane32_swap_b32 %0, %1" : "+v"(x), "+v"(y));
}

// async 16B global -> LDS (wave-uniform lds base + lane*16; global per-lane)
static __device__ __forceinline__ void gll16(const unsigned short* g,
                                             const unsigned short* l) {
    __builtin_amdgcn_global_load_lds(
        (const __attribute__((address_space(1))) unsigned int*)g,
        (__attribute__((address_space(3))) unsigned int*)l,
        16, 0, 0);
}

// ---------------------------------------------------------------------------
// fused fp32 -> bf16 conversion of all six tensors + cumsum (single launch)
// ---------------------------------------------------------------------------
__global__ __launch_bounds__(256) void xattn_convert_all(
    const float* __restrict__ queries, const float* __restrict__ patches,
    const float* __restrict__ wq, const float* __restrict__ wk,
    const float* __restrict__ wv, const float* __restrict__ wo,
    unsigned short* __restrict__ qb, unsigned short* __restrict__ pb,
    unsigned short* __restrict__ wqb, unsigned short* __restrict__ wkb,
    unsigned short* __restrict__ wvb, unsigned short* __restrict__ wob,
    const int* __restrict__ bounds, int* __restrict__ pidx) {
    if (blockIdx.x >= NCONV) {
        // ---- cumsum path: one block per batch, 256 threads x 16 elems ----
        __shared__ int sdata[256];
        int b = blockIdx.x - NCONV;
        int t = threadIdx.x;
        const int* src = bounds + b * S_ + t * 16;
        int vals[16];
        int run = 0;
#pragma unroll
        for (int i = 0; i < 16; ++i) { run += src[i]; vals[i] = run; }
        sdata[t] = run;
        __syncthreads();
        for (int off = 1; off < 256; off <<= 1) {
            int v = (t >= off) ? sdata[t - off] : 0;
            __syncthreads();
            sdata[t] += v;
            __syncthreads();
        }
        int prefix = (t > 0) ? sdata[t - 1] : 0;
        int* dst = pidx + b * S_ + t * 16;
#pragma unroll
        for (int i = 0; i < 16; ++i) dst[i] = prefix + vals[i];
        return;
    }
    // ---- convert path ----
    const int NQ = (B_ * S_ * D_) / 4;      // 2097152
    const int NP = (B_ * P_ * D_) / 4;      // 524288
    const int NW = (D_ * D_) / 4;           // 262144
    int i = blockIdx.x * 256 + threadIdx.x;
    const float* src;
    unsigned short* dst;
    int j;
    if (i < NQ) { src = queries; dst = qb; j = i; }
    else if (i < NQ + NP) { src = patches; dst = pb; j = i - NQ; }
    else {
        int k = i - NQ - NP;
        int wsel = k >> 18;                  // NW = 2^18
        j = k & (NW - 1);
        if (wsel == 0) { src = wq; dst = wqb; }
        else if (wsel == 1) { src = wk; dst = wkb; }
        else if (wsel == 2) { src = wv; dst = wvb; }
        else { src = wo; dst = wob; }
    }
    float4 v = ((const float4*)src)[j];
    ushort4 o;
    o.x = f2bf(v.x); o.y = f2bf(v.y); o.z = f2bf(v.z); o.w = f2bf(v.w);
    ((ushort4*)dst)[j] = o;
}

// ---------------------------------------------------------------------------
// Fused QKV projection: 128x128 tile, dbuf gll staging + counted vmcnt,
// XOR-swizzled LDS, BK=32, 4 waves.
// Grid dim3(8, 96): y<64 -> Q-proj (M=8192, bf16 out * KSCALE, row-major)
//                   y in [64,80) -> K-proj -> FRAGMENT-LINEAR Kf
//                   y in [80,96) -> V-proj -> FRAGMENT-LINEAR Vf
// Fragment-linear layouts (per b,h,ptile of 64 patches; 4096 shorts each):
//   Kf: [at(2)][ks(4)][lane(64)][j(8)]   lane=((k>>3)&1)*32+(p&31), j=k&7,
//       at=(p>>5)&1, ks=(k>>4)&3   (A-operand of S^T = mfma(K,Q))
//   Vf: [dt(2)][ps(4)][lane(64)][j(8)]   lane=((p>>3)&1)*32+(d&31), j=p&7,
//       dt=d>>5, ps=(p>>4)&3        (B-operand of PV)
// ---------------------------------------------------------------------------
__global__ __launch_bounds__(256) void xattn_gemm_qkv(
    const unsigned short* __restrict__ qb, const unsigned short* __restrict__ pb,
    const unsigned short* __restrict__ wqb, const unsigned short* __restrict__ wkb,
    const unsigned short* __restrict__ wvb,
    const float* __restrict__ bq, const float* __restrict__ bk,
    const float* __restrict__ bv,
    unsigned short* __restrict__ Qout, unsigned short* __restrict__ Kout,
    unsigned short* __restrict__ Vout) {
    const int K = 1024, N = 1024;
    const int byy = blockIdx.y;
    int z, my;
    if (byy < 64)      { z = 0; my = byy; }
    else if (byy < 80) { z = 1; my = byy - 64; }
    else               { z = 2; my = byy - 80; }
    const unsigned short* A = (z == 0) ? qb : pb;
    const unsigned short* W = (z == 0) ? wqb : ((z == 1) ? wkb : wvb);
    const float* bias = (z == 0) ? bq : ((z == 1) ? bk : bv);

    __shared__ unsigned short As[2][128 * 32];
    __shared__ unsigned short Bs[2][128 * 32];

    const int m0 = my * 128;
    const int n0 = blockIdx.x * 128;
    const int t = threadIdx.x;
    const int w = t >> 6;
    const int l = t & 63;
    const int fr = l & 15, fq = l >> 4;
    const int wr = w >> 1, wc = w & 1;

    const int r0s = t >> 2;
    const int csw = ((t & 3) ^ ((t >> 3) & 3)) * 8;   // pre-swizzled source
    const unsigned short* Ap0 = A + (size_t)(m0 + r0s) * K + csw;
    const unsigned short* Ap1 = A + (size_t)(m0 + 64 + r0s) * K + csw;
    const unsigned short* Wp0 = W + (size_t)(n0 + r0s) * K + csw;
    const unsigned short* Wp1 = W + (size_t)(n0 + 64 + r0s) * K + csw;

    const int gsw = (fq ^ ((fr >> 1) & 3)) * 8;       // swizzled read granule

    f32x4 acc[4][4];
#pragma unroll
    for (int i = 0; i < 4; ++i)
#pragma unroll
        for (int j = 0; j < 4; ++j) acc[i][j] = (f32x4){0.f, 0.f, 0.f, 0.f};

    // prologue: stage K-step 0 into buffer 0
    gll16(Ap0, &As[0][w * 512]);
    gll16(Ap1, &As[0][2048 + w * 512]);
    gll16(Wp0, &Bs[0][w * 512]);
    gll16(Wp1, &Bs[0][2048 + w * 512]);

    for (int kt = 0; kt < 32; ++kt) {
        __builtin_amdgcn_s_barrier();     // prev iter's readers done
        if (kt + 1 < 32) {
            const int nb = (kt + 1) & 1;
            const int ks = (kt + 1) * 32;
            gll16(Ap0 + ks, &As[nb][w * 512]);
            gll16(Ap1 + ks, &As[nb][2048 + w * 512]);
            gll16(Wp0 + ks, &Bs[nb][w * 512]);
            gll16(Wp1 + ks, &Bs[nb][2048 + w * 512]);
            asm volatile("s_waitcnt vmcnt(4)" ::: "memory");
        } else {
            asm volatile("s_waitcnt vmcnt(0)" ::: "memory");
        }
        __builtin_amdgcn_sched_barrier(0);
        __builtin_amdgcn_s_barrier();     // all waves' step-kt stage complete

        const unsigned short* Ac = As[kt & 1];
        const unsigned short* Bc = Bs[kt & 1];
        short8 af[4], bf[4];
#pragma unroll
        for (int i = 0; i < 4; ++i)
            af[i] = *(const short8*)&Ac[(wr * 64 + i * 16 + fr) * 32 + gsw];
#pragma unroll
        for (int j = 0; j < 4; ++j)
            bf[j] = *(const short8*)&Bc[(wc * 64 + j * 16 + fr) * 32 + gsw];
        __builtin_amdgcn_s_setprio(1);
#pragma unroll
        for (int i = 0; i < 4; ++i)
#pragma unroll
            for (int j = 0; j < 4; ++j)
                acc[i][j] = __builtin_amdgcn_mfma_f32_16x16x32_bf16(af[i], bf[j], acc[i][j], 0, 0, 0);
        __builtin_amdgcn_s_setprio(0);
    }

#pragma unroll
    for (int j = 0; j < 4; ++j) {
        int n = n0 + wc * 64 + j * 16 + fr;
        float bvv = bias[n];
#pragma unroll
        for (int i = 0; i < 4; ++i) {
            int mbase = m0 + wr * 64 + i * 16 + fq * 4;
#pragma unroll
            for (int r = 0; r < 4; ++r) {
                float val = acc[i][j][r] + bvv;
                int m = mbase + r;
                if (z == 0) {
                    Qout[(size_t)m * N + n] = f2bf(val * KSCALE);
                } else if (z == 1) {
                    int bb = m >> 10, p = m & (P_ - 1);
                    int hh = n >> 6, k = n & 63;
                    size_t base = ((size_t)((bb * H_ + hh) * 16 + (p >> 6))) * 4096;
                    int off = (((p >> 5) & 1) * 4 + (k >> 4)) * 512 +
                              (((k >> 3) & 1) * 32 + (p & 31)) * 8 + (k & 7);
                    Kout[base + off] = f2bf(val);
                } else {
                    int bb = m >> 10, p = m & (P_ - 1);
                    int hh = n >> 6, d = n & 63;
                    size_t base = ((size_t)((bb * H_ + hh) * 16 + (p >> 6))) * 4096;
                    int off = ((d >> 5) * 4 + ((p >> 4) & 3)) * 512 +
                              ((((p >> 3) & 1) * 32) + (d & 31)) * 8 + (p & 7);
                    Vout[base + off] = f2bf(val);
                }
            }
        }
    }
}

// ---------------------------------------------------------------------------
// 128x128-tile GEMM, dbuf gll staging + counted vmcnt, XOR-swizzled LDS,
// fp32 out (O projection). Unchanged from R9.
// ---------------------------------------------------------------------------
__global__ __launch_bounds__(256) void xattn_gemm_o(
    const unsigned short* __restrict__ A,
    const unsigned short* __restrict__ W,
    const float* __restrict__ bias,
    float* __restrict__ Cout) {
    const int K = 1024, N = 1024;
    __shared__ unsigned short As[2][128 * 32];
    __shared__ unsigned short Bs[2][128 * 32];

    const int m0 = blockIdx.y * 128;
    const int n0 = blockIdx.x * 128;
    const int t = threadIdx.x;
    const int w = t >> 6;
    const int l = t & 63;
    const int fr = l & 15, fq = l >> 4;
    const int wr = w >> 1, wc = w & 1;

    const int r0s = t >> 2;
    const int csw = ((t & 3) ^ ((t >> 3) & 3)) * 8;   // pre-swizzled source
    const unsigned short* Ap0 = A + (size_t)(m0 + r0s) * K + csw;
    const unsigned short* Ap1 = A + (size_t)(m0 + 64 + r0s) * K + csw;
    const unsigned short* Wp0 = W + (size_t)(n0 + r0s) * K + csw;
    const unsigned short* Wp1 = W + (size_t)(n0 + 64 + r0s) * K + csw;

    const int gsw = (fq ^ ((fr >> 1) & 3)) * 8;       // swizzled read granule

    f32x4 acc[4][4];
#pragma unroll
    for (int i = 0; i < 4; ++i)
#pragma unroll
        for (int j = 0; j < 4; ++j) acc[i][j] = (f32x4){0.f, 0.f, 0.f, 0.f};

    // prologue: stage K-step 0 into buffer 0
    gll16(Ap0, &As[0][w * 512]);
    gll16(Ap1, &As[0][2048 + w * 512]);
    gll16(Wp0, &Bs[0][w * 512]);
    gll16(Wp1, &Bs[0][2048 + w * 512]);

    for (int kt = 0; kt < 32; ++kt) {
        __builtin_amdgcn_s_barrier();
        if (kt + 1 < 32) {
            const int nb = (kt + 1) & 1;
            const int ks = (kt + 1) * 32;
            gll16(Ap0 + ks, &As[nb][w * 512]);
            gll16(Ap1 + ks, &As[nb][2048 + w * 512]);
            gll16(Wp0 + ks, &Bs[nb][w * 512]);
            gll16(Wp1 + ks, &Bs[nb][2048 + w * 512]);
            asm volatile("s_waitcnt vmcnt(4)" ::: "memory");
        } else {
            asm volatile("s_waitcnt vmcnt(0)" ::: "memory");
        }
        __builtin_amdgcn_sched_barrier(0);
        __builtin_amdgcn_s_barrier();

        const unsigned short* Ac = As[kt & 1];
        const unsigned short* Bc = Bs[kt & 1];
        short8 af[4], bf[4];
#pragma unroll
        for (int i = 0; i < 4; ++i)
            af[i] = *(const short8*)&Ac[(wr * 64 + i * 16 + fr) * 32 + gsw];
#pragma unroll
        for (int j = 0; j < 4; ++j)
            bf[j] = *(const short8*)&Bc[(wc * 64 + j * 16 + fr) * 32 + gsw];
        __builtin_amdgcn_s_setprio(1);
#pragma unroll
        for (int i = 0; i < 4; ++i)
#pragma unroll
            for (int j = 0; j < 4; ++j)
                acc[i][j] = __builtin_amdgcn_mfma_f32_16x16x32_bf16(af[i], bf[j], acc[i][j], 0, 0, 0);
        __builtin_amdgcn_s_setprio(0);
    }

#pragma unroll
    for (int j = 0; j < 4; ++j) {
        int n = n0 + wc * 64 + j * 16 + fr;
        float bvv = bias[n];
#pragma unroll
        for (int i = 0; i < 4; ++i) {
            int mbase = m0 + wr * 64 + i * 16 + fq * 4;
#pragma unroll
            for (int r = 0; r < 4; ++r)
                Cout[(size_t)(mbase + r) * N + n] = acc[i][j][r] + bvv;
        }
    }
}

// ---------------------------------------------------------------------------
// MFMA flash attention, round 10: 32x32x16 swapped-QK, in-register softmax.
// Block = 4 waves x 32 q-rows = 128 q. Per 64-patch tile, per wave:
//   S^T = mfma(K,Q): 2 at-frags x 4 ks = 8 MFMA32; lane owns q = l&31,
//     holds 32 of 64 p values (partner lane l^32 holds the rest).
//   exp2 + boundary mask + lsum (scalar per lane).
//   P -> bf16 A-frags: 16 v_cvt_pk_bf16_f32 + 8 v_permlane32_swap_b32.
//   PV: 2 dt-frags x 4 ps = 8 MFMA32 (V frag-linear from LDS).
// All LDS reads lane-linear ds_read_b128 (zero bank conflicts by design).
// ---------------------------------------------------------------------------
__global__ __launch_bounds__(256) void xattn_attn_mfma(
    const unsigned short* __restrict__ Qb,   // [B*S][D] bf16 (pre-scaled)
    const unsigned short* __restrict__ Kf,   // frag-linear (see gemm_qkv)
    const unsigned short* __restrict__ Vf,   // frag-linear
    const int* __restrict__ pidx,
    unsigned short* __restrict__ Ob) {       // [B*S][D] bf16
    __shared__ unsigned short Ks[2][4096];
    __shared__ unsigned short Vs[2][4096];

    const int q0 = (31 - blockIdx.x) * 128;  // LPT: heavy blocks first
    const int h = blockIdx.y;
    const int b = blockIdx.z;
    const int t = threadIdx.x;
    const int w = t >> 6, l = t & 63;
    const int lq = l & 31, lh = l >> 5;
    const int qw = q0 + w * 32;

    // Q B-frags (col = lq, k = ks*16 + lh*8 + j), loaded once
    const unsigned short* qrow =
        Qb + (size_t)(b * S_ + qw + lq) * D_ + h * DH_ + lh * 8;
    short8 qf[4];
#pragma unroll
    for (int ks = 0; ks < 4; ++ks) qf[ks] = *(const short8*)(qrow + ks * 16);

    const int prow = pidx[b * S_ + qw + lq];        // this lane's q row
    const int limit = pidx[b * S_ + q0 + 127];      // monotone in s
    const int ntiles = (min(limit, P_ - 1) + 64) >> 6;
    const int nfull = (pidx[b * S_ + q0] + 1) >> 6; // tiles needing no mask

    float l4[4] = {0.f, 0.f, 0.f, 0.f};
    f32x16 oacc[2] = {{}, {}};

    // staging: wave w moves 1KB chunks 2w, 2w+1 of each 8KB frag tile
    const unsigned short* kfb =
        Kf + (size_t)((b * H_ + h) * 16) * 4096 + (2 * w) * 512 + l * 8;
    const unsigned short* vfb =
        Vf + (size_t)((b * H_ + h) * 16) * 4096 + (2 * w) * 512 + l * 8;

    // prologue: stage tile 0 into buffer 0
    gll16(kfb, &Ks[0][(2 * w) * 512]);
    gll16(kfb + 512, &Ks[0][(2 * w + 1) * 512]);
    gll16(vfb, &Vs[0][(2 * w) * 512]);
    gll16(vfb + 512, &Vs[0][(2 * w + 1) * 512]);

    for (int kt = 0; kt < ntiles; ++kt) {
        // B1: all waves done reading buf[kt&1 ^1] -> safe to refill
        __builtin_amdgcn_s_barrier();
        if (kt + 1 < ntiles) {
            const int nb = (kt + 1) & 1;
            const unsigned short* kn = kfb + (size_t)(kt + 1) * 4096;
            const unsigned short* vn = vfb + (size_t)(kt + 1) * 4096;
            gll16(kn, &Ks[nb][(2 * w) * 512]);
            gll16(kn + 512, &Ks[nb][(2 * w + 1) * 512]);
            gll16(vn, &Vs[nb][(2 * w) * 512]);
            gll16(vn + 512, &Vs[nb][(2 * w + 1) * 512]);
            asm volatile("s_waitcnt vmcnt(4)" ::: "memory");
        } else {
            asm volatile("s_waitcnt vmcnt(0)" ::: "memory");
        }
        __builtin_amdgcn_sched_barrier(0);
        // B2: every wave's tile-kt stage is complete
        __builtin_amdgcn_s_barrier();

        const unsigned short* Kc = Ks[kt & 1];
        const unsigned short* Vc = Vs[kt & 1];
        const int c0 = kt * 64;

        // S^T = K . Q^T  (rows p via regs, cols q = lq)
        f32x16 sa[2];
        __builtin_amdgcn_s_setprio(1);
#pragma unroll
        for (int at = 0; at < 2; ++at) {
            f32x16 a = {};
#pragma unroll
            for (int ks = 0; ks < 4; ++ks) {
                short8 kfr = *(const short8*)&Kc[(at * 4 + ks) * 512 + l * 8];
                a = __builtin_amdgcn_mfma_f32_32x32x16_bf16(kfr, qf[ks], a, 0, 0, 0);
            }
            sa[at] = a;
        }
        __builtin_amdgcn_s_setprio(0);

        // exp2 + boundary mask + lsum (p5(r) = (r&3)+8*(r>>2)+4*lh)
        if (kt >= nfull) {
#pragma unroll
            for (int at = 0; at < 2; ++at)
#pragma unroll
                for (int r = 0; r < 16; ++r) {
                    const int pg = c0 + at * 32 + (r & 3) + 8 * (r >> 2) + 4 * lh;
                    float p = EXP2(sa[at][r]);
                    p = (pg > prow) ? 0.f : p;
                    sa[at][r] = p;
                    l4[r & 3] += p;
                }
        } else {
#pragma unroll
            for (int at = 0; at < 2; ++at)
#pragma unroll
                for (int r = 0; r < 16; ++r) {
                    float p = EXP2(sa[at][r]);
                    sa[at][r] = p;
                    l4[r & 3] += p;
                }
        }

        // pack P into PV A-frags: word m of step ps = bf16 pair
        // p = ps*16 + lh*8 + 2m (+1); own-half pack + permlane32_swap
        short8 pa[4];
#pragma unroll
        for (int ps = 0; ps < 4; ++ps) {
            const int pt = ps >> 1;
            const int rA = (ps & 1) * 8;
            unsigned int X0 = cvtpk(sa[pt][rA + 0], sa[pt][rA + 1]);
            unsigned int Y0 = cvtpk(sa[pt][rA + 4], sa[pt][rA + 5]);
            unsigned int X1 = cvtpk(sa[pt][rA + 2], sa[pt][rA + 3]);
            unsigned int Y1 = cvtpk(sa[pt][rA + 6], sa[pt][rA + 7]);
            plswap(X0, Y0);   // X0 -> word m=0, Y0 -> word m=2
            plswap(X1, Y1);   // X1 -> word m=1, Y1 -> word m=3
            uint4 u = {X0, X1, Y0, Y1};
            pa[ps] = *(short8*)&u;
        }

        // PV: O[q][d] += P . V
        __builtin_amdgcn_s_setprio(1);
#pragma unroll
        for (int dt = 0; dt < 2; ++dt)
#pragma unroll
            for (int ps = 0; ps < 4; ++ps) {
                short8 vfr = *(const short8*)&Vc[(dt * 4 + ps) * 512 + l * 8];
                oacc[dt] = __builtin_amdgcn_mfma_f32_32x32x16_bf16(pa[ps], vfr, oacc[dt], 0, 0, 0);
            }
        __builtin_amdgcn_s_setprio(0);
    }

    // softmax denominator: own 32 p-values + partner half
    float lsum = (l4[0] + l4[1]) + (l4[2] + l4[3]);
    lsum += __shfl_xor(lsum, 32);
    const float inv = 1.0f / lsum;

    unsigned short* ob = Ob + (size_t)(b * S_ + qw) * D_ + h * DH_;
#pragma unroll
    for (int r = 0; r < 16; ++r) {
        const int qr = (r & 3) + 8 * (r >> 2) + 4 * lh;
        const float invr = __shfl(inv, qr);
        ob[(size_t)qr * D_ + lq] = f2bf(oacc[0][r] * invr);
        ob[(size_t)qr * D_ + 32 + lq] = f2bf(oacc[1][r] * invr);
    }
}

// ---------------------------------------------------------------------------
// launch
// ---------------------------------------------------------------------------
extern "C" void kernel_launch(void* const* d_in, const int* in_sizes, int n_in,
                              void* d_out, int out_size, void* d_ws, size_t ws_size,
                              hipStream_t stream) {
    const float* queries = (const float*)d_in[0];
    const float* patches = (const float*)d_in[1];
    const int* bounds    = (const int*)d_in[2];
    const float* wq = (const float*)d_in[3];
    const float* wk = (const float*)d_in[4];
    const float* wv = (const float*)d_in[5];
    const float* wo = (const float*)d_in[6];
    const float* bq = (const float*)d_in[7];
    const float* bk = (const float*)d_in[8];
    const float* bv = (const float*)d_in[9];
    const float* bo = (const float*)d_in[10];
    float* out = (float*)d_out;

    char* ws = (char*)d_ws;
    unsigned short* qb    = (unsigned short*)(ws + 0);          // 16777216
    unsigned short* pb    = (unsigned short*)(ws + 16777216);   // 4194304
    unsigned short* wqb   = (unsigned short*)(ws + 20971520);   // 2097152
    unsigned short* wkb   = (unsigned short*)(ws + 23068672);
    unsigned short* wvb   = (unsigned short*)(ws + 25165824);
    unsigned short* wob   = (unsigned short*)(ws + 27262976);
    unsigned short* Qbf   = (unsigned short*)(ws + 29360128);   // 16777216
    unsigned short* Kfr   = (unsigned short*)(ws + 46137344);   // 4194304
    unsigned short* Vfr   = (unsigned short*)(ws + 50331648);   // 4194304
    unsigned short* attnb = (unsigned short*)(ws + 54525952);   // 16777216
    int* pidx             = (int*)(ws + 71303168);              // 32768

    // 1. fused converts + cumsum
    xattn_convert_all<<<dim3(NCONV + B_), 256, 0, stream>>>(
        queries, patches, wq, wk, wv, wo, qb, pb, wqb, wkb, wvb, wob,
        bounds, pidx);
    // 2. fused Q/K/V projections (K/V emitted fragment-linear)
    xattn_gemm_qkv<<<dim3(8, 96), 256, 0, stream>>>(
        qb, pb, wqb, wkb, wvb, bq, bk, bv, Qbf, Kfr, Vfr);
    // 3. MFMA flash attention (32x32 swapped-QK, in-register softmax)
    xattn_attn_mfma<<<dim3(S_ / 128, H_, B_), 256, 0, stream>>>(
        Qbf, Kfr, Vfr, pidx, attnb);
    // 4. output projection (fp32 out, dbuf pipeline)
    xattn_gemm_o<<<dim3(8, 64), 256, 0, stream>>>(attnb, wob, bo, out);
}